// Round 3
// baseline (214.123 us; speedup 1.0000x reference)
//
#include <hip/hip_runtime.h>

#define T_TOK  16384
#define IN_F   1024
#define OUT_F  1024
#define NE     8
#define BM     128
#define BN     128
#define BK     32
#define NTHREADS 256
#define ROW_TILE_SLOTS 136   // max sum of ceil(len_e/128) = 128 + 8

typedef __bf16 bf16;
typedef bf16  bf16x4 __attribute__((ext_vector_type(4)));
typedef bf16  bf16x8 __attribute__((ext_vector_type(8)));
typedef float f32x4  __attribute__((ext_vector_type(4)));

// Grouped GEMM y[t] = x[t] @ W[e(t)]^T, contiguous ragged segments.
// Inputs fp32, OUTPUT fp32 (reference dtypes); compute in bf16 MFMA.
// 128x128 C tile, BK=32; fp32 global -> VGPR -> cvt bf16 -> LDS staging.
__global__ __launch_bounds__(NTHREADS)
void grouped_gemm_f32io_bf16(const float* __restrict__ x,
                             const float* __restrict__ wgt,
                             const int*  __restrict__ seg_lens,
                             float* __restrict__ out)
{
    __shared__ __align__(16) bf16 As[BM * BK];
    __shared__ __align__(16) bf16 Bs[BN * BK];

    const int m    = blockIdx.y;          // row-tile slot
    const int col0 = blockIdx.x * BN;     // output-feature tile

    // ---- slot m -> (expert, row0, valid rows); segments are contiguous ----
    int e_sel = -1, row0 = 0, rows = 0;
    {
        int start = 0, acct = 0;
        #pragma unroll
        for (int e = 0; e < NE; ++e) {
            int len = seg_lens[e];
            int nt  = (len + BM - 1) >> 7;
            if (e_sel < 0 && m >= acct && m < acct + nt) {
                e_sel = e;
                row0  = start + (m - acct) * BM;
                int rem = start + len - row0;
                rows = rem < BM ? rem : BM;
            }
            acct  += nt;
            start += len;
        }
    }
    if (e_sel < 0) return;   // surplus slot (block-uniform exit, before barriers)

    const int tid  = threadIdx.x;
    const int lane = tid & 63;
    const int wave = tid >> 6;
    const int wm   = (wave >> 1) * 64;   // wave row offset in 128x128 tile
    const int wn   = (wave & 1) * 64;    // wave col offset
    const int quad = lane >> 4;          // 0..3
    const int l16  = lane & 15;

    const float* wbase = wgt + ((size_t)e_sel * OUT_F + (size_t)col0) * IN_F;

    f32x4 acc[4][4] = {};

    for (int k0 = 0; k0 < IN_F; k0 += BK) {
        // ---- global fp32 loads first (overlap with previous iter's tail) ----
        // A/B tiles: 128 rows x 32 floats = 1024 chunks of 16B each; 4/thread.
        f32x4 a_st[4], b_st[4];
        #pragma unroll
        for (int t = 0; t < 4; ++t) {
            int c  = t * NTHREADS + tid;        // chunk id: row=c>>3, kq=c&7
            int rg = row0 + (c >> 3);
            if (rg > T_TOK - 1) rg = T_TOK - 1; // clamp partial last tile
            a_st[t] = *(const f32x4*)(x + (size_t)rg * IN_F + k0 + (c & 7) * 4);
            b_st[t] = *(const f32x4*)(wbase + (size_t)(c >> 3) * IN_F + k0 + (c & 7) * 4);
        }

        __syncthreads();  // previous iteration's ds_reads done before restage

        #pragma unroll
        for (int t = 0; t < 4; ++t) {
            int c = t * NTHREADS + tid;
            bf16x4 ha, hb;
            #pragma unroll
            for (int j = 0; j < 4; ++j) { ha[j] = (bf16)a_st[t][j]; hb[j] = (bf16)b_st[t][j]; }
            *(bf16x4*)(&As[(c >> 3) * BK + (c & 7) * 4]) = ha;   // ds_write_b64
            *(bf16x4*)(&Bs[(c >> 3) * BK + (c & 7) * 4]) = hb;
        }
        __syncthreads();

        // ---- fragments: A[m=l16][k=quad*8+j], B[n=l16][k=quad*8+j] ----
        bf16x8 af[4], bfr[4];
        #pragma unroll
        for (int t = 0; t < 4; ++t)
            af[t] = *(const bf16x8*)(&As[(wm + t * 16 + l16) * BK + quad * 8]);
        #pragma unroll
        for (int u = 0; u < 4; ++u)
            bfr[u] = *(const bf16x8*)(&Bs[(wn + u * 16 + l16) * BK + quad * 8]);

        #pragma unroll
        for (int t = 0; t < 4; ++t)
            #pragma unroll
            for (int u = 0; u < 4; ++u)
                acc[t][u] = __builtin_amdgcn_mfma_f32_16x16x32_bf16(
                    af[t], bfr[u], acc[t][u], 0, 0, 0);
    }

    // ---- epilogue: C/D layout col=lane&15, row=quad*4+reg (m89/m91) ----
    // Output is fp32 (reference dtype) — store accumulator directly.
    #pragma unroll
    for (int t = 0; t < 4; ++t) {
        #pragma unroll
        for (int r = 0; r < 4; ++r) {
            int row = wm + t * 16 + quad * 4 + r;
            if (row < rows) {
                size_t ob = (size_t)(row0 + row) * OUT_F + col0;
                #pragma unroll
                for (int u = 0; u < 4; ++u)
                    out[ob + wn + u * 16 + l16] = acc[t][u][r];
            }
        }
    }
}

extern "C" void kernel_launch(void* const* d_in, const int* in_sizes, int n_in,
                              void* d_out, int out_size, void* d_ws, size_t ws_size,
                              hipStream_t stream) {
    const float* x   = (const float*)d_in[0];
    const float* wgt = (const float*)d_in[1];
    const int*   seg = (const int*)d_in[2];
    float* out = (float*)d_out;

    dim3 grid(OUT_F / BN, ROW_TILE_SLOTS, 1);
    dim3 block(NTHREADS, 1, 1);
    grouped_gemm_f32io_bf16<<<grid, block, 0, stream>>>(x, wgt, seg, out);
}